// Round 7
// baseline (305.383 us; speedup 1.0000x reference)
//
#include <hip/hip_runtime.h>
#include <hip/hip_bf16.h>
#include <stdint.h>

typedef __hip_bfloat16 bf16;
typedef __bf16 bf16x8 __attribute__((ext_vector_type(8)));
typedef float floatx4 __attribute__((ext_vector_type(4)));

#define MFMA16(a, b, c) __builtin_amdgcn_mfma_f32_16x16x32_bf16((a), (b), (c), 0, 0, 0)

typedef __attribute__((address_space(3))) uint32_t lds_u32;
typedef const __attribute__((address_space(1))) uint32_t gbl_u32;

__device__ __forceinline__ void async16(const void* g, void* s) {
    __builtin_amdgcn_global_load_lds((gbl_u32*)g, (lds_u32*)s, 16, 0, 0);
}

// fp32 -> bf16 RNE (scalar)
__device__ __forceinline__ unsigned short f2bf_rne(float f) {
    union { float f; unsigned u; } v; v.f = f;
    const unsigned u = v.u;
    return (unsigned short)((u + 0x7FFFu + ((u >> 16) & 1u)) >> 16);
}
// packed pair: v_cvt_pk_bf16_f32 on gfx950
__device__ __forceinline__ unsigned pk2(float a, float b) {
    __hip_bfloat162 h = __float22bfloat162_rn(make_float2(a, b));
    return *(unsigned*)&h;
}

// ---------------------------------------------------------------------------
// arena element offsets: X 8M | Wq 1M | Wk 1M | Wv 1M | Wo 1M  (bf16)
// ---------------------------------------------------------------------------
#define A_X   0L
#define A_WQ  8388608L
#define A_WK  9437184L
#define A_WV  10485760L
#define A_WO  11534336L
#define A_END 12582912L

__global__ __launch_bounds__(256) void cvt5(
    const float* __restrict__ s0, const float* __restrict__ s1,
    const float* __restrict__ s2, const float* __restrict__ s3,
    const float* __restrict__ s4, unsigned short* __restrict__ dst)
{
    const long beg[6] = {A_X, A_WQ, A_WK, A_WV, A_WO, A_END};
    const float* srcs[5] = {s0, s1, s2, s3, s4};
    const long nchunk = A_END / 8;
    for (long c = (long)blockIdx.x * 256 + threadIdx.x; c < nchunk;
         c += (long)gridDim.x * 256) {
        const long off = c * 8;
        int s = 0;
#pragma unroll
        for (int i = 1; i < 5; ++i) if (off >= beg[i]) s = i;
        const float* sp = srcs[s] + (off - beg[s]);
        const uint4 lo = *(const uint4*)(sp);
        const uint4 hi = *(const uint4*)(sp + 4);
        const float* fl = (const float*)&lo;
        const float* fh = (const float*)&hi;
        uint4 o;
        o.x = pk2(fl[0], fl[1]); o.y = pk2(fl[2], fl[3]);
        o.z = pk2(fh[0], fh[1]); o.w = pk2(fh[2], fh[3]);
        *(uint4*)(dst + off) = o;
    }
}

// ---------------------------------------------------------------------------
// GEMM (m97 structure, validated R4-R6): C = A W^T + b
// TRANSV: which==2 output (V) written transposed as VT[b][h][d][key].
// (XCD swizzle stays reverted: R12 measured it -12 us.)
// ---------------------------------------------------------------------------
template <int CFP32, int TRANSV>
__global__ __launch_bounds__(256, 2) void gemm_bt3(
    const bf16* __restrict__ A,
    const bf16* __restrict__ W0, const bf16* __restrict__ W1, const bf16* __restrict__ W2,
    const float* __restrict__ b0, const float* __restrict__ b1, const float* __restrict__ b2,
    void* __restrict__ C0, void* __restrict__ C1, void* __restrict__ C2)
{
    __shared__ bf16 As[128 * 64];
    __shared__ bf16 Bs[128 * 64];

    const int tid = threadIdx.x;
    const int which = blockIdx.y >> 3;
    const int nt = blockIdx.y & 7;
    const bf16* __restrict__ W   = (which == 0) ? W0 : ((which == 1) ? W1 : W2);
    const float* __restrict__ bb = (which == 0) ? b0 : ((which == 1) ? b1 : b2);
    void* __restrict__ C         = (which == 0) ? C0 : ((which == 1) ? C1 : C2);

    const int m0 = blockIdx.x * 128;
    const int n0 = nt * 128;

    const int w  = tid >> 6;
    const int l  = tid & 63;
    const int lr = l & 15;
    const int q  = l >> 4;
    const int wm = (w & 1) * 64;
    const int wn = (w >> 1) * 64;
    const int wbase = tid & 0xC0;

    floatx4 acc[4][4];
#pragma unroll
    for (int i = 0; i < 4; ++i)
#pragma unroll
        for (int j = 0; j < 4; ++j)
            acc[i][j] = (floatx4){0.f, 0.f, 0.f, 0.f};

#pragma unroll 1
    for (int kt = 0; kt < 16; ++kt) {
        __syncthreads();
#pragma unroll
        for (int r = 0; r < 4; ++r) {
            const int u   = r * 256 + tid;
            const int row = u >> 3;
            const int kg  = u & 7;
            const int kgg = kg ^ (row & 7);
            const size_t goffA = (size_t)(m0 + row) * 1024 + kt * 64 + kgg * 8;
            const size_t goffB = (size_t)(n0 + row) * 1024 + kt * 64 + kgg * 8;
            bf16* dA = As + (size_t)(r * 256 + wbase) * 8;
            bf16* dB = Bs + (size_t)(r * 256 + wbase) * 8;
            async16(A + goffA, dA);
            async16(W + goffB, dB);
        }
        asm volatile("s_waitcnt vmcnt(0)" ::: "memory");
        __syncthreads();

#pragma unroll
        for (int ks = 0; ks < 2; ++ks) {
            bf16x8 av[4], bv[4];
#pragma unroll
            for (int i = 0; i < 4; ++i) {
                const int row = wm + i * 16 + lr;
                const int kg  = (ks * 4 + q) ^ (row & 7);
                av[i] = *(const bf16x8*)(As + row * 64 + kg * 8);
            }
#pragma unroll
            for (int j = 0; j < 4; ++j) {
                const int row = wn + j * 16 + lr;
                const int kg  = (ks * 4 + q) ^ (row & 7);
                bv[j] = *(const bf16x8*)(Bs + row * 64 + kg * 8);
            }
#pragma unroll
            for (int i = 0; i < 4; ++i)
#pragma unroll
                for (int j = 0; j < 4; ++j)
                    acc[i][j] = MFMA16(av[i], bv[j], acc[i][j]);
        }
    }

    if (TRANSV && which == 2) {
        // V transposed store: col -> (h, d); row -> (b, key); 4 keys packed.
#pragma unroll
        for (int j = 0; j < 4; ++j) {
            const int col = n0 + wn + j * 16 + lr;
            const float bj = bb[col];
            const int h = col >> 6, d = col & 63;
#pragma unroll
            for (int i = 0; i < 4; ++i) {
                const int row0 = m0 + wm + i * 16 + q * 4;
                const int b = row0 >> 11;
                const int key = row0 & 2047;
                uint2 ov;
                ov.x = pk2(acc[i][j][0] + bj, acc[i][j][1] + bj);
                ov.y = pk2(acc[i][j][2] + bj, acc[i][j][3] + bj);
                *(uint2*)((unsigned short*)C +
                          ((size_t)(b * 16 + h) * 64 + d) * 2048 + key) = ov;
            }
        }
    } else {
#pragma unroll
        for (int j = 0; j < 4; ++j) {
            const int col = n0 + wn + j * 16 + lr;
            const float bj = bb[col];
#pragma unroll
            for (int i = 0; i < 4; ++i) {
#pragma unroll
                for (int r = 0; r < 4; ++r) {
                    const int row = m0 + wm + i * 16 + q * 4 + r;
                    const float val = acc[i][j][r] + bj;
                    if (CFP32)
                        ((float*)C)[(long)row * 1024 + col] = val;
                    else
                        ((unsigned short*)C)[(long)row * 1024 + col] = f2bf_rne(val);
                }
            }
        }
    }
}

// ---------------------------------------------------------------------------
// Flash attention, S^T formulation, in-register P, single-BB tile body.
// R14 (resubmit after infra failure): dual-i (32 q-rows/wave, R11's LDS
// economy: every kb/va ds_read feeds 2 MFMAs) x 8-wave 512-thread block
// (R13's occupancy). Block covers 256 q-rows; grid (8,64) = 512 blocks =
// exactly 2/CU. Aggregate LDS traffic back to R11's level (~50% LDS-busy
// vs R13's ~85%) at ~2x R11's residency. launch_bounds(512,4) pins
// allocator <=128 unified regs.
// Kept: permuted K-rows, reg-staged prefetch + tail ds_writes, single
// barrier/tile, defer-max THR=8 (one branch), bare exp2, z4 MFMA init,
// vectorized lsum, max3 trees, setprio on MFMA bursts.
// ---------------------------------------------------------------------------
__device__ __forceinline__ int swzk(int R) {
    return (R & 7) ^ (((R >> 3) & 1) << 2);
}

__global__ __launch_bounds__(512, 4) void attn_flash(
    const bf16* __restrict__ Q, const bf16* __restrict__ K, const bf16* __restrict__ VT,
    bf16* __restrict__ AO)
{
    __shared__ bf16 Ks[2 * 64 * 64];
    __shared__ bf16 Vt[2 * 64 * 64];   // Vt[d][key]

    const int tid = threadIdx.x;
    const int b = blockIdx.y >> 4, h = blockIdx.y & 15;
    const int q0 = blockIdx.x * 256;
    const size_t base = ((size_t)b * 2048) * 1024 + (size_t)h * 64;
    const size_t vtb  = (size_t)(b * 16 + h) * 64 * 2048;

    const int w  = tid >> 6;     // 0..7: wave owns q-rows w*32 .. w*32+31
    const int l  = tid & 63;
    const int lr = l & 15;
    const int q  = l >> 4;

    // staging geometry (512 threads cover the full 64x64 tile, 16B each)
    const int srow = tid >> 3;   // 0..63
    const int soct = tid & 7;
    const int stK = srow * 64 + ((soct ^ swzk(srow)) * 8);
    const int stV = srow * 64 + ((soct ^ (srow & 7)) * 8);

    // Q fragments in registers (reused all 32 iterations): B-frag layout
    bf16x8 qb[2][2];
#pragma unroll
    for (int i = 0; i < 2; ++i)
#pragma unroll
        for (int ks = 0; ks < 2; ++ks)
            qb[i][ks] = *(const bf16x8*)(Q + base +
                (size_t)(q0 + w * 32 + i * 16 + lr) * 1024 + ks * 32 + q * 8);

    // load tile 0 into registers and stage to buffer 0
    uint4 kreg = *(const uint4*)(K + base + (size_t)srow * 1024 + soct * 8);
    uint4 vreg = *(const uint4*)(VT + vtb + (size_t)srow * 2048 + soct * 8);
    *(uint4*)(Ks + stK) = kreg;
    *(uint4*)(Vt + stV) = vreg;

    const floatx4 z4 = (floatx4){0.f, 0.f, 0.f, 0.f};
    floatx4 O0[4], O1[4];
#pragma unroll
    for (int d = 0; d < 4; ++d) { O0[d] = z4; O1[d] = z4; }
    float m0 = -1e30f, m1 = -1e30f;
    floatx4 ls0v = z4, ls1v = z4;
    const float cs = 0.18033688011112042f;  // log2(e)/sqrt(64)

#pragma unroll 1
    for (int kt = 0; kt < 32; ++kt) {
        __syncthreads();   // tile kt's staging (tail of kt-1 / prologue) visible
        const int bsel = (kt & 1) * 4096;
        const int bnxt = 4096 - bsel;

        // prefetch next tile (clamped: kt=31 redundantly reloads tile 31)
        const int ktn = (kt < 31) ? (kt + 1) : 31;
        kreg = *(const uint4*)(K + base + (size_t)ktn * 65536 +
                               (size_t)srow * 1024 + soct * 8);
        vreg = *(const uint4*)(VT + vtb + (size_t)srow * 2048 +
                               (size_t)ktn * 64 + soct * 8);

        // S^T = K Q^T with permuted key rows: lane (q,lr) ends up holding
        // key = (t&1)*32 + q*8 + (t>>1)*4 + r  for s{i}[t][r].
        bf16x8 kb0[4], kb1[4];
#pragma unroll
        for (int t = 0; t < 4; ++t) {
            const int R = (t & 1) * 32 + (t >> 1) * 4 + (lr >> 2) * 8 + (lr & 3);
            kb0[t] = *(const bf16x8*)(Ks + bsel + R * 64 + ((q ^ swzk(R)) * 8));
            kb1[t] = *(const bf16x8*)(Ks + bsel + R * 64 + (((4 + q) ^ swzk(R)) * 8));
        }
        floatx4 s0[4], s1[4];
        __builtin_amdgcn_s_setprio(1);
#pragma unroll
        for (int t = 0; t < 4; ++t) s0[t] = MFMA16(kb0[t], qb[0][0], z4);
#pragma unroll
        for (int t = 0; t < 4; ++t) s0[t] = MFMA16(kb1[t], qb[0][1], s0[t]);
#pragma unroll
        for (int t = 0; t < 4; ++t) s1[t] = MFMA16(kb0[t], qb[1][0], z4);
#pragma unroll
        for (int t = 0; t < 4; ++t) s1[t] = MFMA16(kb1[t], qb[1][1], s1[t]);
        __builtin_amdgcn_s_setprio(0);

        // local 16-value max trees (nested triples -> v_max3_f32)
        float a0 = fmaxf(fmaxf(s0[0][0], s0[0][1]), s0[0][2]);
        float a1 = fmaxf(fmaxf(s0[0][3], s0[1][0]), s0[1][1]);
        float a2 = fmaxf(fmaxf(s0[1][2], s0[1][3]), s0[2][0]);
        float a3 = fmaxf(fmaxf(s0[2][1], s0[2][2]), s0[2][3]);
        float a4 = fmaxf(fmaxf(s0[3][0], s0[3][1]), s0[3][2]);
        const float mt0 = fmaxf(fmaxf(fmaxf(a0, a1), fmaxf(a2, a3)),
                                fmaxf(a4, s0[3][3])) * cs;
        float c0 = fmaxf(fmaxf(s1[0][0], s1[0][1]), s1[0][2]);
        float c1 = fmaxf(fmaxf(s1[0][3], s1[1][0]), s1[1][1]);
        float c2 = fmaxf(fmaxf(s1[1][2], s1[1][3]), s1[2][0]);
        float c3 = fmaxf(fmaxf(s1[2][1], s1[2][2]), s1[2][3]);
        float c4 = fmaxf(fmaxf(s1[3][0], s1[3][1]), s1[3][2]);
        const float mt1 = fmaxf(fmaxf(fmaxf(c0, c1), fmaxf(c2, c3)),
                                fmaxf(c4, s1[3][3])) * cs;

        // ONE defer-branch per tile (T13, THR=8): rescale both i when needed
        if (__any((mt0 > m0 + 8.f) || (mt1 > m1 + 8.f))) {
            float vr0 = fmaxf(mt0, __shfl_xor(mt0, 16));
            vr0 = fmaxf(vr0, __shfl_xor(vr0, 32));
            const float mn0 = fmaxf(m0, vr0);
            const float al0 = __builtin_amdgcn_exp2f(m0 - mn0);
            m0 = mn0; ls0v *= al0;
#pragma unroll
            for (int d = 0; d < 4; ++d) O0[d] *= al0;
            float vr1 = fmaxf(mt1, __shfl_xor(mt1, 16));
            vr1 = fmaxf(vr1, __shfl_xor(vr1, 32));
            const float mn1 = fmaxf(m1, vr1);
            const float al1 = __builtin_amdgcn_exp2f(m1 - mn1);
            m1 = mn1; ls1v *= al1;
#pragma unroll
            for (int d = 0; d < 4; ++d) O1[d] *= al1;
        }

        // issue V fragment reads for kc=0 (latency hidden under exp0)
        bf16x8 va0[4];
#pragma unroll
        for (int dt = 0; dt < 4; ++dt) {
            const int R = dt * 16 + lr;
            va0[dt] = *(const bf16x8*)(Vt + bsel + R * 64 + ((q ^ (R & 7)) * 8));
        }

        // exp + vectorized row-sum + pack, i = 0
#pragma unroll
        for (int t = 0; t < 4; ++t)
#pragma unroll
            for (int r = 0; r < 4; ++r)
                s0[t][r] = __builtin_amdgcn_exp2f(s0[t][r] * cs - m0);
        ls0v += (s0[0] + s0[1]) + (s0[2] + s0[3]);
        bf16x8 pb0[2];
#pragma unroll
        for (int kc = 0; kc < 2; ++kc) {
            union { uint4 u; bf16x8 v; } pw;
            pw.u.x = pk2(s0[kc][0], s0[kc][1]);
            pw.u.y = pk2(s0[kc][2], s0[kc][3]);
            pw.u.z = pk2(s0[kc + 2][0], s0[kc + 2][1]);
            pw.u.w = pk2(s0[kc + 2][2], s0[kc + 2][3]);
            pb0[kc] = pw.v;
        }

        // PV i=0, kc=0
        __builtin_amdgcn_s_setprio(1);
#pragma unroll
        for (int dt = 0; dt < 4; ++dt) O0[dt] = MFMA16(va0[dt], pb0[0], O0[dt]);
        __builtin_amdgcn_s_setprio(0);

        // issue V fragment reads for kc=1 (latency hidden under exp1)
        bf16x8 va1[4];
#pragma unroll
        for (int dt = 0; dt < 4; ++dt) {
            const int R = dt * 16 + lr;
            va1[dt] = *(const bf16x8*)(Vt + bsel + R * 64 +
                                       (((4 + q) ^ (R & 7)) * 8));
        }

        // exp + vectorized row-sum + pack, i = 1
#pragma unroll
        for (int t = 0; t < 4; ++t)
#pragma unroll
            for (int r = 0; r < 4; ++r)
                s1[t][r] = __builtin_amdgcn_exp2f(s1[t][r] * cs - m1);
        ls1v += (s1[0] + s1[1]) + (s1[2] + s1[3]);
        bf16x8 pb1[2];
#pragma unroll
        for (int kc = 0; kc < 2; ++kc) {
            union { uint4 u; bf16x8 v; } pw;
            pw.u.x = pk2(s1[kc][0], s1[kc][1]);
            pw.u.y = pk2(s1[kc][2], s1[kc][3]);
            pw.u.z = pk2(s1[kc + 2][0], s1[kc + 2][1]);
            pw.u.w = pk2(s1[kc + 2][2], s1[kc + 2][3]);
            pb1[kc] = pw.v;
        }

        // remaining PV MFMAs: i=0 kc=1, i=1 kc=0/1 (va shared across i)
        __builtin_amdgcn_s_setprio(1);
#pragma unroll
        for (int dt = 0; dt < 4; ++dt) O0[dt] = MFMA16(va1[dt], pb0[1], O0[dt]);
#pragma unroll
        for (int dt = 0; dt < 4; ++dt) O1[dt] = MFMA16(va0[dt], pb1[0], O1[dt]);
#pragma unroll
        for (int dt = 0; dt < 4; ++dt) O1[dt] = MFMA16(va1[dt], pb1[1], O1[dt]);
        __builtin_amdgcn_s_setprio(0);

        // tail staging: next tile -> other buffer (race-free: that buffer's
        // last readers finished before barrier(kt), already crossed; writes
        // drain via the lgkm wait of barrier(kt+1))
        *(uint4*)(Ks + bnxt + stK) = kreg;
        *(uint4*)(Vt + bnxt + stV) = vreg;
    }

    // epilogue: lane holds qrow = q0+w*32+i*16+lr, d = dt*16+q*4+r
    {
        float ls = (ls0v[0] + ls0v[1]) + (ls0v[2] + ls0v[3]);
        ls += __shfl_xor(ls, 16);
        ls += __shfl_xor(ls, 32);
        const float inv = 1.f / ls;
        const int row = q0 + w * 32 + lr;
#pragma unroll
        for (int dt = 0; dt < 4; ++dt) {
            uint2 oh;
            oh.x = pk2(O0[dt][0] * inv, O0[dt][1] * inv);
            oh.y = pk2(O0[dt][2] * inv, O0[dt][3] * inv);
            *(uint2*)((unsigned short*)AO + base + (size_t)row * 1024 +
                      dt * 16 + q * 4) = oh;
        }
    }
    {
        float ls = (ls1v[0] + ls1v[1]) + (ls1v[2] + ls1v[3]);
        ls += __shfl_xor(ls, 16);
        ls += __shfl_xor(ls, 32);
        const float inv = 1.f / ls;
        const int row = q0 + w * 32 + 16 + lr;
#pragma unroll
        for (int dt = 0; dt < 4; ++dt) {
            uint2 oh;
            oh.x = pk2(O1[dt][0] * inv, O1[dt][1] * inv);
            oh.y = pk2(O1[dt][2] * inv, O1[dt][3] * inv);
            *(uint2*)((unsigned short*)AO + base + (size_t)row * 1024 +
                      dt * 16 + q * 4) = oh;
        }
    }
}

extern "C" void kernel_launch(void* const* d_in, const int* in_sizes, int n_in,
                              void* d_out, int out_size, void* d_ws, size_t ws_size,
                              hipStream_t stream) {
    (void)in_sizes; (void)n_in; (void)out_size; (void)ws_size;
    const float* X  = (const float*)d_in[0];
    const float* Wq = (const float*)d_in[1];
    const float* bq = (const float*)d_in[2];
    const float* Wk = (const float*)d_in[3];
    const float* bk = (const float*)d_in[4];
    const float* Wv = (const float*)d_in[5];
    const float* bv = (const float*)d_in[6];
    const float* Wo = (const float*)d_in[7];
    const float* bo = (const float*)d_in[8];
    float* out = (float*)d_out;

    unsigned short* arena = (unsigned short*)d_ws;
    bf16* Xb  = (bf16*)(arena + A_X);
    bf16* Wqb = (bf16*)(arena + A_WQ);
    bf16* Wkb = (bf16*)(arena + A_WK);
    bf16* Wvb = (bf16*)(arena + A_WV);
    bf16* Wob = (bf16*)(arena + A_WO);

    const size_t SZ = (size_t)8192 * 1024;
    bf16* Qb  = (bf16*)(arena + A_END);
    bf16* Kb  = Qb + SZ;
    bf16* VTb = Kb + SZ;      // V stored transposed [b][h][d][key]
    bf16* AOb = VTb + SZ;

    cvt5<<<dim3(1536), dim3(256), 0, stream>>>(X, Wq, Wk, Wv, Wo, arena);

    gemm_bt3<0, 1><<<dim3(64, 24), dim3(256), 0, stream>>>(
        Xb, Wqb, Wkb, Wvb, bq, bk, bv, (void*)Qb, (void*)Kb, (void*)VTb);

    attn_flash<<<dim3(8, 64), dim3(512), 0, stream>>>(Qb, Kb, VTb, AOb);

    gemm_bt3<1, 0><<<dim3(64, 8), dim3(256), 0, stream>>>(
        AOb, Wob, Wob, Wob, bo, bo, bo, (void*)out, (void*)out, (void*)out);
}

// Round 8
// 263.526 us; speedup vs baseline: 1.1588x; 1.1588x over previous
//
#include <hip/hip_runtime.h>
#include <hip/hip_bf16.h>
#include <stdint.h>

typedef __hip_bfloat16 bf16;
typedef __bf16 bf16x8 __attribute__((ext_vector_type(8)));
typedef float floatx4 __attribute__((ext_vector_type(4)));

#define MFMA16(a, b, c) __builtin_amdgcn_mfma_f32_16x16x32_bf16((a), (b), (c), 0, 0, 0)

typedef __attribute__((address_space(3))) uint32_t lds_u32;
typedef const __attribute__((address_space(1))) uint32_t gbl_u32;

__device__ __forceinline__ void async16(const void* g, void* s) {
    __builtin_amdgcn_global_load_lds((gbl_u32*)g, (lds_u32*)s, 16, 0, 0);
}

// fp32 -> bf16 RNE (scalar)
__device__ __forceinline__ unsigned short f2bf_rne(float f) {
    union { float f; unsigned u; } v; v.f = f;
    const unsigned u = v.u;
    return (unsigned short)((u + 0x7FFFu + ((u >> 16) & 1u)) >> 16);
}
// packed pair: v_cvt_pk_bf16_f32 on gfx950
__device__ __forceinline__ unsigned pk2(float a, float b) {
    __hip_bfloat162 h = __float22bfloat162_rn(make_float2(a, b));
    return *(unsigned*)&h;
}

// ---------------------------------------------------------------------------
// arena element offsets: X 8M | Wq 1M | Wk 1M | Wv 1M | Wo 1M  (bf16)
// ---------------------------------------------------------------------------
#define A_X   0L
#define A_WQ  8388608L
#define A_WK  9437184L
#define A_WV  10485760L
#define A_WO  11534336L
#define A_END 12582912L

__global__ __launch_bounds__(256) void cvt5(
    const float* __restrict__ s0, const float* __restrict__ s1,
    const float* __restrict__ s2, const float* __restrict__ s3,
    const float* __restrict__ s4, unsigned short* __restrict__ dst)
{
    const long beg[6] = {A_X, A_WQ, A_WK, A_WV, A_WO, A_END};
    const float* srcs[5] = {s0, s1, s2, s3, s4};
    const long nchunk = A_END / 8;
    for (long c = (long)blockIdx.x * 256 + threadIdx.x; c < nchunk;
         c += (long)gridDim.x * 256) {
        const long off = c * 8;
        int s = 0;
#pragma unroll
        for (int i = 1; i < 5; ++i) if (off >= beg[i]) s = i;
        const float* sp = srcs[s] + (off - beg[s]);
        const uint4 lo = *(const uint4*)(sp);
        const uint4 hi = *(const uint4*)(sp + 4);
        const float* fl = (const float*)&lo;
        const float* fh = (const float*)&hi;
        uint4 o;
        o.x = pk2(fl[0], fl[1]); o.y = pk2(fl[2], fl[3]);
        o.z = pk2(fh[0], fh[1]); o.w = pk2(fh[2], fh[3]);
        *(uint4*)(dst + off) = o;
    }
}

// ---------------------------------------------------------------------------
// GEMM (m97 structure, validated R4-R6): C = A W^T + b
// TRANSV: which==2 output (V) written transposed as VT[b][h][d][key].
// (XCD swizzle stays reverted: R12 measured it -12 us.)
// ---------------------------------------------------------------------------
template <int CFP32, int TRANSV>
__global__ __launch_bounds__(256, 2) void gemm_bt3(
    const bf16* __restrict__ A,
    const bf16* __restrict__ W0, const bf16* __restrict__ W1, const bf16* __restrict__ W2,
    const float* __restrict__ b0, const float* __restrict__ b1, const float* __restrict__ b2,
    void* __restrict__ C0, void* __restrict__ C1, void* __restrict__ C2)
{
    __shared__ bf16 As[128 * 64];
    __shared__ bf16 Bs[128 * 64];

    const int tid = threadIdx.x;
    const int which = blockIdx.y >> 3;
    const int nt = blockIdx.y & 7;
    const bf16* __restrict__ W   = (which == 0) ? W0 : ((which == 1) ? W1 : W2);
    const float* __restrict__ bb = (which == 0) ? b0 : ((which == 1) ? b1 : b2);
    void* __restrict__ C         = (which == 0) ? C0 : ((which == 1) ? C1 : C2);

    const int m0 = blockIdx.x * 128;
    const int n0 = nt * 128;

    const int w  = tid >> 6;
    const int l  = tid & 63;
    const int lr = l & 15;
    const int q  = l >> 4;
    const int wm = (w & 1) * 64;
    const int wn = (w >> 1) * 64;
    const int wbase = tid & 0xC0;

    floatx4 acc[4][4];
#pragma unroll
    for (int i = 0; i < 4; ++i)
#pragma unroll
        for (int j = 0; j < 4; ++j)
            acc[i][j] = (floatx4){0.f, 0.f, 0.f, 0.f};

#pragma unroll 1
    for (int kt = 0; kt < 16; ++kt) {
        __syncthreads();
#pragma unroll
        for (int r = 0; r < 4; ++r) {
            const int u   = r * 256 + tid;
            const int row = u >> 3;
            const int kg  = u & 7;
            const int kgg = kg ^ (row & 7);
            const size_t goffA = (size_t)(m0 + row) * 1024 + kt * 64 + kgg * 8;
            const size_t goffB = (size_t)(n0 + row) * 1024 + kt * 64 + kgg * 8;
            bf16* dA = As + (size_t)(r * 256 + wbase) * 8;
            bf16* dB = Bs + (size_t)(r * 256 + wbase) * 8;
            async16(A + goffA, dA);
            async16(W + goffB, dB);
        }
        asm volatile("s_waitcnt vmcnt(0)" ::: "memory");
        __syncthreads();

#pragma unroll
        for (int ks = 0; ks < 2; ++ks) {
            bf16x8 av[4], bv[4];
#pragma unroll
            for (int i = 0; i < 4; ++i) {
                const int row = wm + i * 16 + lr;
                const int kg  = (ks * 4 + q) ^ (row & 7);
                av[i] = *(const bf16x8*)(As + row * 64 + kg * 8);
            }
#pragma unroll
            for (int j = 0; j < 4; ++j) {
                const int row = wn + j * 16 + lr;
                const int kg  = (ks * 4 + q) ^ (row & 7);
                bv[j] = *(const bf16x8*)(Bs + row * 64 + kg * 8);
            }
#pragma unroll
            for (int i = 0; i < 4; ++i)
#pragma unroll
                for (int j = 0; j < 4; ++j)
                    acc[i][j] = MFMA16(av[i], bv[j], acc[i][j]);
        }
    }

    if (TRANSV && which == 2) {
        // V transposed store: col -> (h, d); row -> (b, key); 4 keys packed.
#pragma unroll
        for (int j = 0; j < 4; ++j) {
            const int col = n0 + wn + j * 16 + lr;
            const float bj = bb[col];
            const int h = col >> 6, d = col & 63;
#pragma unroll
            for (int i = 0; i < 4; ++i) {
                const int row0 = m0 + wm + i * 16 + q * 4;
                const int b = row0 >> 11;
                const int key = row0 & 2047;
                uint2 ov;
                ov.x = pk2(acc[i][j][0] + bj, acc[i][j][1] + bj);
                ov.y = pk2(acc[i][j][2] + bj, acc[i][j][3] + bj);
                *(uint2*)((unsigned short*)C +
                          ((size_t)(b * 16 + h) * 64 + d) * 2048 + key) = ov;
            }
        }
    } else {
#pragma unroll
        for (int j = 0; j < 4; ++j) {
            const int col = n0 + wn + j * 16 + lr;
            const float bj = bb[col];
#pragma unroll
            for (int i = 0; i < 4; ++i) {
#pragma unroll
                for (int r = 0; r < 4; ++r) {
                    const int row = m0 + wm + i * 16 + q * 4 + r;
                    const float val = acc[i][j][r] + bj;
                    if (CFP32)
                        ((float*)C)[(long)row * 1024 + col] = val;
                    else
                        ((unsigned short*)C)[(long)row * 1024 + col] = f2bf_rne(val);
                }
            }
        }
    }
}

// ---------------------------------------------------------------------------
// Flash attention, S^T formulation, in-register P, single-BB tile body.
// R15: R14's dual-i x 8-wave structure with the REGISTER CAP FIXED.
// R14 post-mortem: __launch_bounds__(512,4) => allocator targeted
// 32 waves/CU (8/SIMD) => 64-VGPR cap => ~20 MB scratch spill/dispatch
// (WRITE_SIZE 16->34 MB), VALUBusy collapsed to 46%. Empirical rule from
// R7/R8/R13/R14: waves/CU ~= arg x block-waves. (512,2) => 16 waves/CU
// => 128-VGPR cap: dual-i's ~112 regs fit spill-free, 2 blocks/CU.
// Kept: permuted K-rows, in-reg P, reg-staged prefetch + tail ds_writes,
// single barrier/tile, defer-max THR=8, bare exp2, z4 MFMA init,
// vectorized lsum, max3 trees, setprio on MFMA bursts.
// ---------------------------------------------------------------------------
__device__ __forceinline__ int swzk(int R) {
    return (R & 7) ^ (((R >> 3) & 1) << 2);
}

__global__ __launch_bounds__(512, 2) void attn_flash(
    const bf16* __restrict__ Q, const bf16* __restrict__ K, const bf16* __restrict__ VT,
    bf16* __restrict__ AO)
{
    __shared__ bf16 Ks[2 * 64 * 64];
    __shared__ bf16 Vt[2 * 64 * 64];   // Vt[d][key]

    const int tid = threadIdx.x;
    const int b = blockIdx.y >> 4, h = blockIdx.y & 15;
    const int q0 = blockIdx.x * 256;
    const size_t base = ((size_t)b * 2048) * 1024 + (size_t)h * 64;
    const size_t vtb  = (size_t)(b * 16 + h) * 64 * 2048;

    const int w  = tid >> 6;     // 0..7: wave owns q-rows w*32 .. w*32+31
    const int l  = tid & 63;
    const int lr = l & 15;
    const int q  = l >> 4;

    // staging geometry (512 threads cover the full 64x64 tile, 16B each)
    const int srow = tid >> 3;   // 0..63
    const int soct = tid & 7;
    const int stK = srow * 64 + ((soct ^ swzk(srow)) * 8);
    const int stV = srow * 64 + ((soct ^ (srow & 7)) * 8);

    // Q fragments in registers (reused all 32 iterations): B-frag layout
    bf16x8 qb[2][2];
#pragma unroll
    for (int i = 0; i < 2; ++i)
#pragma unroll
        for (int ks = 0; ks < 2; ++ks)
            qb[i][ks] = *(const bf16x8*)(Q + base +
                (size_t)(q0 + w * 32 + i * 16 + lr) * 1024 + ks * 32 + q * 8);

    // load tile 0 into registers and stage to buffer 0
    uint4 kreg = *(const uint4*)(K + base + (size_t)srow * 1024 + soct * 8);
    uint4 vreg = *(const uint4*)(VT + vtb + (size_t)srow * 2048 + soct * 8);
    *(uint4*)(Ks + stK) = kreg;
    *(uint4*)(Vt + stV) = vreg;

    const floatx4 z4 = (floatx4){0.f, 0.f, 0.f, 0.f};
    floatx4 O0[4], O1[4];
#pragma unroll
    for (int d = 0; d < 4; ++d) { O0[d] = z4; O1[d] = z4; }
    float m0 = -1e30f, m1 = -1e30f;
    floatx4 ls0v = z4, ls1v = z4;
    const float cs = 0.18033688011112042f;  // log2(e)/sqrt(64)

#pragma unroll 1
    for (int kt = 0; kt < 32; ++kt) {
        __syncthreads();   // tile kt's staging (tail of kt-1 / prologue) visible
        const int bsel = (kt & 1) * 4096;
        const int bnxt = 4096 - bsel;

        // prefetch next tile (clamped: kt=31 redundantly reloads tile 31)
        const int ktn = (kt < 31) ? (kt + 1) : 31;
        kreg = *(const uint4*)(K + base + (size_t)ktn * 65536 +
                               (size_t)srow * 1024 + soct * 8);
        vreg = *(const uint4*)(VT + vtb + (size_t)srow * 2048 +
                               (size_t)ktn * 64 + soct * 8);

        // S^T = K Q^T with permuted key rows: lane (q,lr) ends up holding
        // key = (t&1)*32 + q*8 + (t>>1)*4 + r  for s{i}[t][r].
        bf16x8 kb0[4], kb1[4];
#pragma unroll
        for (int t = 0; t < 4; ++t) {
            const int R = (t & 1) * 32 + (t >> 1) * 4 + (lr >> 2) * 8 + (lr & 3);
            kb0[t] = *(const bf16x8*)(Ks + bsel + R * 64 + ((q ^ swzk(R)) * 8));
            kb1[t] = *(const bf16x8*)(Ks + bsel + R * 64 + (((4 + q) ^ swzk(R)) * 8));
        }
        floatx4 s0[4], s1[4];
        __builtin_amdgcn_s_setprio(1);
#pragma unroll
        for (int t = 0; t < 4; ++t) s0[t] = MFMA16(kb0[t], qb[0][0], z4);
#pragma unroll
        for (int t = 0; t < 4; ++t) s0[t] = MFMA16(kb1[t], qb[0][1], s0[t]);
#pragma unroll
        for (int t = 0; t < 4; ++t) s1[t] = MFMA16(kb0[t], qb[1][0], z4);
#pragma unroll
        for (int t = 0; t < 4; ++t) s1[t] = MFMA16(kb1[t], qb[1][1], s1[t]);
        __builtin_amdgcn_s_setprio(0);

        // local 16-value max trees (nested triples -> v_max3_f32)
        float a0 = fmaxf(fmaxf(s0[0][0], s0[0][1]), s0[0][2]);
        float a1 = fmaxf(fmaxf(s0[0][3], s0[1][0]), s0[1][1]);
        float a2 = fmaxf(fmaxf(s0[1][2], s0[1][3]), s0[2][0]);
        float a3 = fmaxf(fmaxf(s0[2][1], s0[2][2]), s0[2][3]);
        float a4 = fmaxf(fmaxf(s0[3][0], s0[3][1]), s0[3][2]);
        const float mt0 = fmaxf(fmaxf(fmaxf(a0, a1), fmaxf(a2, a3)),
                                fmaxf(a4, s0[3][3])) * cs;
        float c0 = fmaxf(fmaxf(s1[0][0], s1[0][1]), s1[0][2]);
        float c1 = fmaxf(fmaxf(s1[0][3], s1[1][0]), s1[1][1]);
        float c2 = fmaxf(fmaxf(s1[1][2], s1[1][3]), s1[2][0]);
        float c3 = fmaxf(fmaxf(s1[2][1], s1[2][2]), s1[2][3]);
        float c4 = fmaxf(fmaxf(s1[3][0], s1[3][1]), s1[3][2]);
        const float mt1 = fmaxf(fmaxf(fmaxf(c0, c1), fmaxf(c2, c3)),
                                fmaxf(c4, s1[3][3])) * cs;

        // ONE defer-branch per tile (T13, THR=8): rescale both i when needed
        if (__any((mt0 > m0 + 8.f) || (mt1 > m1 + 8.f))) {
            float vr0 = fmaxf(mt0, __shfl_xor(mt0, 16));
            vr0 = fmaxf(vr0, __shfl_xor(vr0, 32));
            const float mn0 = fmaxf(m0, vr0);
            const float al0 = __builtin_amdgcn_exp2f(m0 - mn0);
            m0 = mn0; ls0v *= al0;
#pragma unroll
            for (int d = 0; d < 4; ++d) O0[d] *= al0;
            float vr1 = fmaxf(mt1, __shfl_xor(mt1, 16));
            vr1 = fmaxf(vr1, __shfl_xor(vr1, 32));
            const float mn1 = fmaxf(m1, vr1);
            const float al1 = __builtin_amdgcn_exp2f(m1 - mn1);
            m1 = mn1; ls1v *= al1;
#pragma unroll
            for (int d = 0; d < 4; ++d) O1[d] *= al1;
        }

        // issue V fragment reads for kc=0 (latency hidden under exp0)
        bf16x8 va0[4];
#pragma unroll
        for (int dt = 0; dt < 4; ++dt) {
            const int R = dt * 16 + lr;
            va0[dt] = *(const bf16x8*)(Vt + bsel + R * 64 + ((q ^ (R & 7)) * 8));
        }

        // exp + vectorized row-sum + pack, i = 0
#pragma unroll
        for (int t = 0; t < 4; ++t)
#pragma unroll
            for (int r = 0; r < 4; ++r)
                s0[t][r] = __builtin_amdgcn_exp2f(s0[t][r] * cs - m0);
        ls0v += (s0[0] + s0[1]) + (s0[2] + s0[3]);
        bf16x8 pb0[2];
#pragma unroll
        for (int kc = 0; kc < 2; ++kc) {
            union { uint4 u; bf16x8 v; } pw;
            pw.u.x = pk2(s0[kc][0], s0[kc][1]);
            pw.u.y = pk2(s0[kc][2], s0[kc][3]);
            pw.u.z = pk2(s0[kc + 2][0], s0[kc + 2][1]);
            pw.u.w = pk2(s0[kc + 2][2], s0[kc + 2][3]);
            pb0[kc] = pw.v;
        }

        // PV i=0, kc=0
        __builtin_amdgcn_s_setprio(1);
#pragma unroll
        for (int dt = 0; dt < 4; ++dt) O0[dt] = MFMA16(va0[dt], pb0[0], O0[dt]);
        __builtin_amdgcn_s_setprio(0);

        // issue V fragment reads for kc=1 (latency hidden under exp1)
        bf16x8 va1[4];
#pragma unroll
        for (int dt = 0; dt < 4; ++dt) {
            const int R = dt * 16 + lr;
            va1[dt] = *(const bf16x8*)(Vt + bsel + R * 64 +
                                       (((4 + q) ^ (R & 7)) * 8));
        }

        // exp + vectorized row-sum + pack, i = 1
#pragma unroll
        for (int t = 0; t < 4; ++t)
#pragma unroll
            for (int r = 0; r < 4; ++r)
                s1[t][r] = __builtin_amdgcn_exp2f(s1[t][r] * cs - m1);
        ls1v += (s1[0] + s1[1]) + (s1[2] + s1[3]);
        bf16x8 pb1[2];
#pragma unroll
        for (int kc = 0; kc < 2; ++kc) {
            union { uint4 u; bf16x8 v; } pw;
            pw.u.x = pk2(s1[kc][0], s1[kc][1]);
            pw.u.y = pk2(s1[kc][2], s1[kc][3]);
            pw.u.z = pk2(s1[kc + 2][0], s1[kc + 2][1]);
            pw.u.w = pk2(s1[kc + 2][2], s1[kc + 2][3]);
            pb1[kc] = pw.v;
        }

        // remaining PV MFMAs: i=0 kc=1, i=1 kc=0/1 (va shared across i)
        __builtin_amdgcn_s_setprio(1);
#pragma unroll
        for (int dt = 0; dt < 4; ++dt) O0[dt] = MFMA16(va1[dt], pb0[1], O0[dt]);
#pragma unroll
        for (int dt = 0; dt < 4; ++dt) O1[dt] = MFMA16(va0[dt], pb1[0], O1[dt]);
#pragma unroll
        for (int dt = 0; dt < 4; ++dt) O1[dt] = MFMA16(va1[dt], pb1[1], O1[dt]);
        __builtin_amdgcn_s_setprio(0);

        // tail staging: next tile -> other buffer (race-free: that buffer's
        // last readers finished before barrier(kt), already crossed; writes
        // drain via the lgkm wait of barrier(kt+1))
        *(uint4*)(Ks + bnxt + stK) = kreg;
        *(uint4*)(Vt + bnxt + stV) = vreg;
    }

    // epilogue: lane holds qrow = q0+w*32+i*16+lr, d = dt*16+q*4+r
    {
        float ls = (ls0v[0] + ls0v[1]) + (ls0v[2] + ls0v[3]);
        ls += __shfl_xor(ls, 16);
        ls += __shfl_xor(ls, 32);
        const float inv = 1.f / ls;
        const int row = q0 + w * 32 + lr;
#pragma unroll
        for (int dt = 0; dt < 4; ++dt) {
            uint2 oh;
            oh.x = pk2(O0[dt][0] * inv, O0[dt][1] * inv);
            oh.y = pk2(O0[dt][2] * inv, O0[dt][3] * inv);
            *(uint2*)((unsigned short*)AO + base + (size_t)row * 1024 +
                      dt * 16 + q * 4) = oh;
        }
    }
    {
        float ls = (ls1v[0] + ls1v[1]) + (ls1v[2] + ls1v[3]);
        ls += __shfl_xor(ls, 16);
        ls += __shfl_xor(ls, 32);
        const float inv = 1.f / ls;
        const int row = q0 + w * 32 + 16 + lr;
#pragma unroll
        for (int dt = 0; dt < 4; ++dt) {
            uint2 oh;
            oh.x = pk2(O1[dt][0] * inv, O1[dt][1] * inv);
            oh.y = pk2(O1[dt][2] * inv, O1[dt][3] * inv);
            *(uint2*)((unsigned short*)AO + base + (size_t)row * 1024 +
                      dt * 16 + q * 4) = oh;
        }
    }
}

extern "C" void kernel_launch(void* const* d_in, const int* in_sizes, int n_in,
                              void* d_out, int out_size, void* d_ws, size_t ws_size,
                              hipStream_t stream) {
    (void)in_sizes; (void)n_in; (void)out_size; (void)ws_size;
    const float* X  = (const float*)d_in[0];
    const float* Wq = (const float*)d_in[1];
    const float* bq = (const float*)d_in[2];
    const float* Wk = (const float*)d_in[3];
    const float* bk = (const float*)d_in[4];
    const float* Wv = (const float*)d_in[5];
    const float* bv = (const float*)d_in[6];
    const float* Wo = (const float*)d_in[7];
    const float* bo = (const float*)d_in[8];
    float* out = (float*)d_out;

    unsigned short* arena = (unsigned short*)d_ws;
    bf16* Xb  = (bf16*)(arena + A_X);
    bf16* Wqb = (bf16*)(arena + A_WQ);
    bf16* Wkb = (bf16*)(arena + A_WK);
    bf16* Wvb = (bf16*)(arena + A_WV);
    bf16* Wob = (bf16*)(arena + A_WO);

    const size_t SZ = (size_t)8192 * 1024;
    bf16* Qb  = (bf16*)(arena + A_END);
    bf16* Kb  = Qb + SZ;
    bf16* VTb = Kb + SZ;      // V stored transposed [b][h][d][key]
    bf16* AOb = VTb + SZ;

    cvt5<<<dim3(1536), dim3(256), 0, stream>>>(X, Wq, Wk, Wv, Wo, arena);

    gemm_bt3<0, 1><<<dim3(64, 24), dim3(256), 0, stream>>>(
        Xb, Wqb, Wkb, Wvb, bq, bk, bv, (void*)Qb, (void*)Kb, (void*)VTb);

    attn_flash<<<dim3(8, 64), dim3(512), 0, stream>>>(Qb, Kb, VTb, AOb);

    gemm_bt3<1, 0><<<dim3(64, 8), dim3(256), 0, stream>>>(
        AOb, Wob, Wob, Wob, bo, bo, bo, (void*)out, (void*)out, (void*)out);
}